// Round 2
// baseline (682.152 us; speedup 1.0000x reference)
//
#include <hip/hip_runtime.h>
#include <cstdint>
#include <cstddef>

#define H 256
#define KCAT 512      // concatenated K (feats|ctx)
#define BM 64         // rows per block in fused_e
#define KT 32         // K-step
#define LDA 40        // padded LDS row stride (bf16 elems) to spread banks

typedef __attribute__((ext_vector_type(8))) short  frag8;     // 8 bf16 in 4 VGPRs
typedef __attribute__((ext_vector_type(8))) unsigned short ushort8;
typedef __attribute__((ext_vector_type(4))) float  f32x4;

__device__ __forceinline__ unsigned short f32_to_bf16(float f) {
    uint32_t u = __float_as_uint(f);
    u = (u + 0x7FFFu + ((u >> 16) & 1u)) >> 16;   // RNE
    return (unsigned short)u;
}

// ---------------- kernel 1: cast Wu|Wv -> bf16 concat [256][512] ----------------
__global__ void cast_weights(const float* __restrict__ Wu, const float* __restrict__ Wv,
                             unsigned short* __restrict__ Wcat) {
    int idx = blockIdx.x * 256 + threadIdx.x;     // 0..131071
    int n = idx >> 9;
    int k = idx & 511;
    float v = (k < 256) ? Wu[n * 256 + k] : Wv[n * 256 + (k - 256)];
    Wcat[idx] = f32_to_bf16(v);
}

// ---------------- kernel 2: WoutT[k][j] = Wout[j][k] ----------------
__global__ void transpose_wout(const float* __restrict__ Wout, float* __restrict__ WoutT) {
    int idx = blockIdx.x * 256 + threadIdx.x;     // coalesced write
    int j = idx & 255, k = idx >> 8;
    WoutT[idx] = Wout[j * 256 + k];
}

// ---------------- kernel 3: exclusive scan of ragged lengths ----------------
// Auto-detects int64 (little-endian) vs int32 storage: lengths are always >0,
// so all-zero odd words => int64.
__global__ void seg_offsets(const int* __restrict__ lens, int B, int* __restrict__ off) {
    __shared__ int part[256];
    int tid = threadIdx.x;
    bool is64 = (B >= 3) && (lens[1] == 0) && (lens[3] == 0) && (lens[5] == 0);
    int per = (B + 255) / 256;
    int base = tid * per;
    int s = 0;
    for (int i = 0; i < per; i++) {
        int idx = base + i;
        if (idx < B) s += is64 ? lens[2 * idx] : lens[idx];
    }
    part[tid] = s;
    __syncthreads();
    for (int d = 1; d < 256; d <<= 1) {
        int v = part[tid];
        int add = (tid >= d) ? part[tid - d] : 0;
        __syncthreads();
        part[tid] = v + add;
        __syncthreads();
    }
    int run = part[tid] - s;   // exclusive prefix
    for (int i = 0; i < per; i++) {
        int idx = base + i;
        if (idx < B) {
            off[idx] = run;
            run += is64 ? lens[2 * idx] : lens[idx];
        }
    }
    if (tid == 255) off[B] = part[255];
}

// ---------------- kernel 4: fused e = We . sigmoid(Wu f + bu + Wv c) ----------------
// Block: 256 threads (4 waves), 64 rows x all 256 cols, K = 512 (feats|ctx concat).
// Wave w owns cols [w*64, w*64+64). bf16 MFMA 16x16x32, f32 accumulate.
__global__ __launch_bounds__(256) void fused_e(
        const float* __restrict__ feats, const float* __restrict__ ctx,
        const unsigned short* __restrict__ Wcat,
        const float* __restrict__ bu, const float* __restrict__ We,
        float* __restrict__ e_out) {
    __shared__ unsigned short a_tile[BM * LDA];   // 5120 B
    __shared__ float bu_lds[H];
    __shared__ float we_lds[H];
    __shared__ float e_acc[BM];

    const int tid = threadIdx.x;
    const size_t m0 = (size_t)blockIdx.x * BM;

    bu_lds[tid] = bu[tid];
    we_lds[tid] = We[tid];
    if (tid < BM) e_acc[tid] = 0.0f;

    const int lane = tid & 63;
    const int w    = tid >> 6;     // wave id: col group
    const int l15  = lane & 15;
    const int q    = lane >> 4;

    f32x4 acc[4][4];
    #pragma unroll
    for (int i = 0; i < 4; i++)
        #pragma unroll
        for (int j = 0; j < 4; j++)
            acc[i][j] = (f32x4)(0.0f);

    const int srow  = tid >> 2;    // 0..63 staging row
    const int spart = tid & 3;     // 0..3 staging 8-elem chunk

    for (int kk = 0; kk < 16; ++kk) {
        const int k0 = kk * KT;
        const float* src = (k0 < 256) ? feats : ctx;
        const int   col  = ((k0 < 256) ? k0 : (k0 - 256)) + spart * 8;
        const float* p = src + (m0 + srow) * H + col;
        f32x4 v0 = *(const f32x4*)p;
        f32x4 v1 = *(const f32x4*)(p + 4);
        ushort8 pk;
        pk[0] = f32_to_bf16(v0[0]); pk[1] = f32_to_bf16(v0[1]);
        pk[2] = f32_to_bf16(v0[2]); pk[3] = f32_to_bf16(v0[3]);
        pk[4] = f32_to_bf16(v1[0]); pk[5] = f32_to_bf16(v1[1]);
        pk[6] = f32_to_bf16(v1[2]); pk[7] = f32_to_bf16(v1[3]);

        __syncthreads();                         // prior reads of a_tile done
        *(ushort8*)&a_tile[srow * LDA + spart * 8] = pk;
        __syncthreads();                         // writes visible

        frag8 afr[4], bfr[4];
        #pragma unroll
        for (int ct = 0; ct < 4; ++ct) {
            int n = w * 64 + ct * 16 + l15;
            bfr[ct] = *(const frag8*)&Wcat[(size_t)n * KCAT + k0 + q * 8];
        }
        #pragma unroll
        for (int rt = 0; rt < 4; ++rt)
            afr[rt] = *(const frag8*)&a_tile[(rt * 16 + l15) * LDA + q * 8];

        #pragma unroll
        for (int rt = 0; rt < 4; ++rt)
            #pragma unroll
            for (int ct = 0; ct < 4; ++ct)
                acc[rt][ct] = __builtin_amdgcn_mfma_f32_16x16x32_bf16(
                    afr[rt], bfr[ct], acc[rt][ct], 0, 0, 0);
    }

    // epilogue: e_row = sum_col We[col] * sigmoid(h + bu[col])
    #pragma unroll
    for (int rt = 0; rt < 4; ++rt) {
        #pragma unroll
        for (int r = 0; r < 4; ++r) {
            int row = rt * 16 + q * 4 + r;
            float s = 0.0f;
            #pragma unroll
            for (int ct = 0; ct < 4; ++ct) {
                int colg = w * 64 + ct * 16 + l15;
                float h  = acc[rt][ct][r] + bu_lds[colg];
                float sg = 1.0f / (1.0f + __expf(-h));
                s += we_lds[colg] * sg;
            }
            s += __shfl_xor(s, 1, 64);
            s += __shfl_xor(s, 2, 64);
            s += __shfl_xor(s, 4, 64);
            s += __shfl_xor(s, 8, 64);
            if (l15 == 0) atomicAdd(&e_acc[row], s);
        }
    }
    __syncthreads();
    if (tid < BM) e_out[m0 + tid] = e_acc[tid];
}

// ---------------- kernel 5: per-segment softmax + weighted pooling ----------------
// NOTE: segment lengths are mostly 20..82 BUT the last segment absorbs the
// flooring deficit of the reference's length rescale: len can be ~2100.
// Everything is grid-stride / chunked — NO len<=256 assumption.
__global__ __launch_bounds__(256) void softmax_pool(
        const float* __restrict__ e, const float* __restrict__ feats,
        const int* __restrict__ off, float* __restrict__ rst) {
    __shared__ float red[256];
    __shared__ float alpha[256];
    const int b = blockIdx.x, tid = threadIdx.x;
    const int start = off[b];
    const int len = off[b + 1] - start;

    // --- segment max (grid-stride) ---
    float mloc = -3.0e38f;
    for (int i = tid; i < len; i += 256) mloc = fmaxf(mloc, e[start + i]);
    red[tid] = mloc;
    __syncthreads();
    for (int s = 128; s > 0; s >>= 1) {
        if (tid < s) red[tid] = fmaxf(red[tid], red[tid + s]);
        __syncthreads();
    }
    float m = red[0];
    __syncthreads();

    // --- sum of exp (grid-stride) ---
    float sloc = 0.0f;
    for (int i = tid; i < len; i += 256) sloc += expf(e[start + i] - m);
    red[tid] = sloc;
    __syncthreads();
    for (int s = 128; s > 0; s >>= 1) {
        if (tid < s) red[tid] += red[tid + s];
        __syncthreads();
    }
    float denom = red[0];
    float inv = (denom > 0.0f) ? 1.0f / denom : 0.0f;
    __syncthreads();

    // --- pooling, 256-item alpha chunks ---
    float acc = 0.0f;
    for (int c = 0; c < len; c += 256) {
        int rem = len - c;
        if (rem > 256) rem = 256;
        if (tid < rem) alpha[tid] = expf(e[start + c + tid] - m) * inv;
        __syncthreads();
        const float* fp = feats + (size_t)(start + c) * H + tid;
        for (int i = 0; i < rem; i++) acc += alpha[i] * fp[(size_t)i * H];
        __syncthreads();
    }
    rst[(size_t)b * H + tid] = acc;
}

// ---------------- kernel 6: out = rst @ Wout.T (via WoutT) ----------------
#define RB 8
__global__ __launch_bounds__(256) void out_gemm(
        const float* __restrict__ rst, const float* __restrict__ WoutT,
        float* __restrict__ out) {
    __shared__ float r[RB * 256];
    const int tid = threadIdx.x;
    const size_t b0 = (size_t)blockIdx.x * RB;
    for (int i = tid; i < RB * 256; i += 256) r[i] = rst[b0 * 256 + i];
    __syncthreads();
    float acc[RB];
    #pragma unroll
    for (int j = 0; j < RB; j++) acc[j] = 0.0f;
    for (int k = 0; k < 256; k += 4) {
        f32x4 rw[RB];
        #pragma unroll
        for (int j = 0; j < RB; j++) rw[j] = *(const f32x4*)&r[j * 256 + k];
        #pragma unroll
        for (int kk = 0; kk < 4; kk++) {
            float wv = WoutT[(size_t)(k + kk) * 256 + tid];
            #pragma unroll
            for (int j = 0; j < RB; j++) acc[j] += rw[j][kk] * wv;
        }
    }
    #pragma unroll
    for (int j = 0; j < RB; j++) out[(b0 + j) * 256 + tid] = acc[j];
}

// ---------------- launch ----------------
extern "C" void kernel_launch(void* const* d_in, const int* in_sizes, int n_in,
                              void* d_out, int out_size, void* d_ws, size_t ws_size,
                              hipStream_t stream) {
    const float* feats = (const float*)d_in[0];
    const float* ctx   = (const float*)d_in[1];
    const int*   lens  = (const int*)d_in[2];
    const float* Wu    = (const float*)d_in[3];
    const float* bu    = (const float*)d_in[4];
    const float* Wv    = (const float*)d_in[5];
    const float* We    = (const float*)d_in[6];
    const float* Wout  = (const float*)d_in[7];
    float* out = (float*)d_out;

    const int N = in_sizes[0] / H;    // 204800
    const int B = in_sizes[2];        // 4096

    // workspace carve-up (256B aligned chunks)
    char* w = (char*)d_ws;
    auto carve = [&](size_t bytes) {
        char* p = w;
        w += (bytes + 255) & ~(size_t)255;
        return p;
    };
    int*            off   = (int*)           carve((size_t)(B + 1) * sizeof(int));
    float*          e     = (float*)         carve((size_t)N * sizeof(float));
    float*          rst   = (float*)         carve((size_t)B * H * sizeof(float));
    unsigned short* Wcat  = (unsigned short*)carve((size_t)H * KCAT * sizeof(unsigned short));
    float*          WoutT = (float*)         carve((size_t)H * H * sizeof(float));

    cast_weights <<<(H * KCAT) / 256, 256, 0, stream>>>(Wu, Wv, Wcat);
    transpose_wout<<<(H * H) / 256,   256, 0, stream>>>(Wout, WoutT);
    seg_offsets  <<<1,                256, 0, stream>>>(lens, B, off);
    fused_e      <<<N / BM,           256, 0, stream>>>(feats, ctx, Wcat, bu, We, e);
    softmax_pool <<<B,                256, 0, stream>>>(e, feats, off, rst);
    out_gemm     <<<B / RB,           256, 0, stream>>>(rst, WoutT, out);
}